// Round 1
// baseline (106.830 us; speedup 1.0000x reference)
//
#include <hip/hip_runtime.h>

// make_blocks: out[b,p,a,c,:] = concat(seq1M[b, r0+c, :], seq2M[b, c0+a, :], geo[b,p,a,c])
// Shapes: B=64, L=2048, D=60, P=16, PS=30, out [B,P,PS,PS,2D+1] fp32.

constexpr int B_    = 64;
constexpr int L_    = 2048;
constexpr int D_    = 60;
constexpr int P_    = 16;
constexpr int PS_   = 30;
constexpr int KOUT  = 2 * D_ + 1;      // 121
constexpr int ROWLEN = PS_ * KOUT;     // 3630 floats per 'a' row
constexpr int CHUNK  = PS_ * PS_ * KOUT; // 108900 floats per (b,p)
constexpr int NV4    = CHUNK / 4;      // 27225 float4 per (b,p)
constexpr int SPLIT  = 2;              // blocks per (b,p)
constexpr int NT     = 256;

__global__ __launch_bounds__(NT) void make_blocks_38860864094557_kernel(
    const float* __restrict__ seq1, const float* __restrict__ seq2,
    const float* __restrict__ geo,  const int* __restrict__ patches,
    float* __restrict__ out)
{
    __shared__ float sh_rows[PS_ * D_];  // 1800 floats: rows[c][d] = seq1M[b, r0+c, d]
    __shared__ float sh_cols[PS_ * D_];  // 1800 floats: cols[a][d] = seq2M[b, c0+a, d]
    __shared__ float sh_geo [PS_ * PS_]; // 900 floats:  geo[a][c]

    const int bid = blockIdx.x;
    const int bp  = bid / SPLIT;         // which (b,p)
    const int s   = bid % SPLIT;         // which half of the chunk
    const int b   = bp / P_;

    const int r0 = patches[bp * 2 + 0];
    const int c0 = patches[bp * 2 + 1];

    // All of these spans are contiguous in memory and 16B-aligned (D=60, PS*PS=900 are %4==0).
    const float4* rsrc = reinterpret_cast<const float4*>(seq1 + ((size_t)b * L_ + r0) * D_);
    const float4* csrc = reinterpret_cast<const float4*>(seq2 + ((size_t)b * L_ + c0) * D_);
    const float4* gsrc = reinterpret_cast<const float4*>(geo  + (size_t)bp * (PS_ * PS_));

    for (int i = threadIdx.x; i < PS_ * D_ / 4; i += NT) {       // 450 float4 each
        reinterpret_cast<float4*>(sh_rows)[i] = rsrc[i];
        reinterpret_cast<float4*>(sh_cols)[i] = csrc[i];
    }
    for (int i = threadIdx.x; i < PS_ * PS_ / 4; i += NT) {      // 225 float4
        reinterpret_cast<float4*>(sh_geo)[i] = gsrc[i];
    }
    __syncthreads();

    float4* dst = reinterpret_cast<float4*>(out + (size_t)bp * CHUNK);
    const int lo = (NV4 * s) / SPLIT;
    const int hi = (NV4 * (s + 1)) / SPLIT;

    for (int i = lo + (int)threadIdx.x; i < hi; i += NT) {
        const unsigned t = 4u * (unsigned)i;
        float4 v;
        float* vp = reinterpret_cast<float*>(&v);
#pragma unroll
        for (int j = 0; j < 4; ++j) {
            const unsigned tj = t + j;
            const unsigned a  = tj / ROWLEN;          // magic-mul div by 3630
            const unsigned r  = tj - a * ROWLEN;
            const unsigned c  = r / KOUT;             // magic-mul div by 121
            const unsigned k  = r - c * KOUT;
            float val;
            if (k < D_)            val = sh_rows[c * D_ + k];
            else if (k < 2 * D_)   val = sh_cols[a * D_ + (k - D_)];
            else                   val = sh_geo[a * PS_ + c];
            vp[j] = val;
        }
        dst[i] = v;  // coalesced 16B stores
    }
}

extern "C" void kernel_launch(void* const* d_in, const int* in_sizes, int n_in,
                              void* d_out, int out_size, void* d_ws, size_t ws_size,
                              hipStream_t stream) {
    const float* seq1    = (const float*)d_in[0];
    const float* seq2    = (const float*)d_in[1];
    const float* geo     = (const float*)d_in[2];
    const int*   patches = (const int*)d_in[3];
    float*       out     = (float*)d_out;

    const int grid = B_ * P_ * SPLIT;  // 2048 blocks
    make_blocks_38860864094557_kernel<<<grid, NT, 0, stream>>>(seq1, seq2, geo, patches, out);
}